// Round 12
// baseline (301.950 us; speedup 1.0000x reference)
//
#include <hip/hip_runtime.h>
#include <math.h>

#define DD 1024
#define BB 8192

__device__ __forceinline__ float softplus_f(float x) {
    return fmaxf(x, 0.0f) + log1pf(expf(-fabsf(x)));
}

template <int CTRL>
__device__ __forceinline__ float dppmov(float x) {
    return __int_as_float(
        __builtin_amdgcn_mov_dpp(__float_as_int(x), CTRL, 0xF, 0xF, true));
}

// cross-lane stages = lane XOR masks {1,2,7,15,16,32}. (R1-R8 validated form.)
__device__ __forceinline__ void fwht1024(float v[16], float sA, float sB,
                                         float sC, float sD, float sE, float sF) {
#pragma unroll
    for (int s = 1; s <= 8; s <<= 1) {
#pragma unroll
        for (int m = 0; m < 16; ++m)
            if ((m & s) == 0) {
                float a = v[m], b = v[m ^ s];
                v[m] = a + b;
                v[m ^ s] = a - b;
            }
    }
#pragma unroll
    for (int m = 0; m < 16; ++m) { float o = dppmov<0xB1>(v[m]);  v[m] = fmaf(v[m], sA, o); } // xor 1
#pragma unroll
    for (int m = 0; m < 16; ++m) { float o = dppmov<0x4E>(v[m]);  v[m] = fmaf(v[m], sB, o); } // xor 2
#pragma unroll
    for (int m = 0; m < 16; ++m) { float o = dppmov<0x141>(v[m]); v[m] = fmaf(v[m], sC, o); } // xor 7
#pragma unroll
    for (int m = 0; m < 16; ++m) { float o = dppmov<0x140>(v[m]); v[m] = fmaf(v[m], sD, o); } // xor 15
#pragma unroll
    for (int m = 0; m < 16; ++m) { float o = __shfl_xor(v[m], 16, 64); v[m] = fmaf(v[m], sE, o); } // xor 16
#pragma unroll
    for (int m = 0; m < 16; ++m) { float o = __shfl_xor(v[m], 32, 64); v[m] = fmaf(v[m], sF, o); } // xor 32
}

// acquire-poll by t0, then block barrier, then device-scope fence by ALL
// threads (emits L2 writeback+invalidate -> kills write-allocate-stale lines
// before any cross-block data is read).
__device__ __forceinline__ void spin_wait(int* flag, int target) {
    if (threadIdx.x == 0) {
        while (__hip_atomic_load(flag, __ATOMIC_ACQUIRE,
                                 __HIP_MEMORY_SCOPE_AGENT) < target)
            __builtin_amdgcn_s_sleep(8);
    }
    __syncthreads();
    __threadfence();
}

// release-publish: every thread fences its own stores, barrier, t0 bumps flag.
__device__ __forceinline__ void publish(int* flag) {
    __threadfence();
    __syncthreads();
    if (threadIdx.x == 0) atomicAdd(flag, 1);
}

// One fused kernel, 512 blocks x 512 threads, 2 blocks/CU (64KB LDS, <=128 VGPR).
// Phase 1 (bid<256):  part2[rg][j]  = partial t sums      (line-aligned writes)
// Phase 2 (bid<32):   tg[j] = sum of 16 partials          (line-aligned writes)
// Phase 3 (bid<256):  u[i] = mu[i] + dot(sp(rho[i,:]),tg) (4 rows/block)
// Phase 4 (all):      FWHT main (R8 body, x prefetched into regs at phase 0)
__global__ __launch_bounds__(512, 4) void k_all(
    const float* __restrict__ x,   const float* __restrict__ s1,
    const float* __restrict__ s2,  const float* __restrict__ mu,
    const float* __restrict__ rho, const float* __restrict__ eps,
    int* __restrict__ flags, float* __restrict__ part2,
    float* __restrict__ tg, float* __restrict__ u, float* __restrict__ out) {
    __shared__ __align__(16) float smem[16 * 1024];
    const int t    = threadIdx.x;
    const int lane = t & 63;
    const int wv   = t >> 6;
    const int bid  = blockIdx.x;        // 512 blocks
    // R8 XCD-paired batch map (full 128B output lines merge in same-XCD L2)
    const int x8   = bid & 7;
    const int q    = bid >> 3;
    const int pair = x8 * 32 + (q >> 1);
    const int b0   = pair * 32 + (q & 1) * 16;

    const int l0 = lane & 1, l1 = (lane >> 1) & 1, l2 = (lane >> 2) & 1,
              l3 = (lane >> 3) & 1, l4 = (lane >> 4) & 1, l5 = (lane >> 5) & 1;
    const int hi = (l0 ^ l2) | ((l1 ^ l2) << 1) | ((l2 ^ l3) << 2) | (l3 << 3) |
                   (l4 << 4) | (l5 << 5);
    const int base = hi << 4;

    // ---- Phase 0: issue x prefetch (2 rows/wave) into registers ----
    const float* xr = x + (size_t)(b0 + wv * 2) * DD + base;
    float4 xva[4], xvb[4];
#pragma unroll
    for (int c = 0; c < 4; ++c) {
        xva[c] = *(const float4*)(xr + 4 * c);
        xvb[c] = *(const float4*)(xr + DD + 4 * c);
    }
    __builtin_amdgcn_sched_barrier(0);   // pin loads before the spin phases

    if (bid < 256) {
        // ---- Phase 1: t-partials (task (cg,rg), 64 cols x 64 rows) ----
        const int cg = bid & 15, rg = bid >> 4;
        const int j = cg * 64 + lane;
        const int rowbase = rg * 64 + wv * 8;
        float acc = 0.f;
#pragma unroll
        for (int k = 0; k < 8; ++k) {
            int row = rowbase + k;
            acc += softplus_f(rho[row * DD + j]) * eps[row];
        }
        smem[wv * 64 + lane] = acc;
        __syncthreads();
        if (t < 64) {
            float s = 0.f;
#pragma unroll
            for (int w = 0; w < 8; ++w) s += smem[w * 64 + t];
            part2[rg * 1024 + cg * 64 + t] = s;   // 256B line-aligned chunk
        }
        publish(&flags[0]);

        // ---- Phase 2: finalize t (32 blocks x 32 js, 128B-aligned writes) ----
        spin_wait(&flags[0], 256);
        if (bid < 32) {
            if (t < 32) {
                int j2 = bid * 32 + t;
                float s = 0.f;
#pragma unroll
                for (int p = 0; p < 16; ++p) s += part2[p * 1024 + j2];
                tg[j2] = s;
            }
            publish(&flags[1]);
        }

        // ---- Phase 3: u (4 rows/block) ----
        spin_wait(&flags[1], 32);
#pragma unroll
        for (int rr = 0; rr < 4; ++rr) {
            const int i = bid * 4 + rr;
            float a = softplus_f(rho[i * DD + t]) * tg[t] +
                      softplus_f(rho[i * DD + t + 512]) * tg[t + 512];
#pragma unroll
            for (int off = 32; off > 0; off >>= 1)
                a += __shfl_down(a, off, 64);
            if (lane == 0) smem[wv * 4 + rr] = a;
        }
        __syncthreads();
        if (t < 4) {
            const int i = bid * 4 + t;
            float s = mu[i];
#pragma unroll
            for (int w = 0; w < 8; ++w) s += smem[w * 4 + t];
            u[i] = s;
        }
        publish(&flags[2]);
    }

    // ---- Phase 4: main FWHT (R8-validated body) ----
    spin_wait(&flags[2], 256);

    const float sA = (l0 ^ l2) ? -1.f : 1.f;
    const float sB = (l1 ^ l2) ? -1.f : 1.f;
    const float sC = (l2 ^ l3) ? -1.f : 1.f;
    const float sD = l3 ? -1.f : 1.f;
    const float sE = l4 ? -1.f : 1.f;
    const float sF = l5 ? -1.f : 1.f;

    float4 s2f[4], uf[4], s1f[4];
#pragma unroll
    for (int c = 0; c < 4; ++c) {
        s2f[c] = *(const float4*)(s2 + base + 4 * c);
        uf[c]  = *(const float4*)(u  + base + 4 * c);
        s1f[c] = *(const float4*)(s1 + base + 4 * c);
        const float kscale = 1.0f / 1024.0f;
        s1f[c].x *= kscale; s1f[c].y *= kscale;
        s1f[c].z *= kscale; s1f[c].w *= kscale;
    }
    const int qsw = hi & 3;

#pragma unroll
    for (int rr = 0; rr < 2; ++rr) {
        const int r = wv * 2 + rr;
        float v[16];
#pragma unroll
        for (int c = 0; c < 4; ++c) {
            float4 xv = (rr == 0) ? xva[c] : xvb[c];
            v[4 * c + 0] = xv.x * s2f[c].x;
            v[4 * c + 1] = xv.y * s2f[c].y;
            v[4 * c + 2] = xv.z * s2f[c].z;
            v[4 * c + 3] = xv.w * s2f[c].w;
        }
        fwht1024(v, sA, sB, sC, sD, sE, sF);
#pragma unroll
        for (int c = 0; c < 4; ++c) {
            v[4 * c + 0] *= uf[c].x;
            v[4 * c + 1] *= uf[c].y;
            v[4 * c + 2] *= uf[c].z;
            v[4 * c + 3] *= uf[c].w;
        }
        fwht1024(v, sA, sB, sC, sD, sE, sF);
        float* trow = smem + r * 1024 + ((hi ^ ((r >> 2) & 3)) << 4);
#pragma unroll
        for (int c = 0; c < 4; ++c) {
            float4 y;
            y.x = fmaxf(v[4 * c + 0] * s1f[c].x, 0.f);
            y.y = fmaxf(v[4 * c + 1] * s1f[c].y, 0.f);
            y.z = fmaxf(v[4 * c + 2] * s1f[c].z, 0.f);
            y.w = fmaxf(v[4 * c + 3] * s1f[c].w, 0.f);
            *(float4*)(trow + 4 * (c ^ qsw)) = y;
        }
    }
    __syncthreads();

#pragma unroll
    for (int it = 0; it < 8; ++it) {
        const int d  = (t >> 2) + (it << 7);
        const int r4 = (t & 3) << 2;
        const int h  = d >> 4;
        const int col = ((h ^ (t & 3)) << 4) + 4 * (((d >> 2) & 3) ^ (h & 3)) +
                        (d & 3);
        float4 y;
        y.x = smem[(r4 + 0) * 1024 + col];
        y.y = smem[(r4 + 1) * 1024 + col];
        y.z = smem[(r4 + 2) * 1024 + col];
        y.w = smem[(r4 + 3) * 1024 + col];
        *(float4*)(out + (size_t)d * BB + b0 + r4) = y;
    }
}

extern "C" void kernel_launch(void* const* d_in, const int* in_sizes, int n_in,
                              void* d_out, int out_size, void* d_ws, size_t ws_size,
                              hipStream_t stream) {
    const float* x   = (const float*)d_in[0];
    const float* s1  = (const float*)d_in[1];
    const float* s2  = (const float*)d_in[2];
    const float* mu  = (const float*)d_in[3];
    const float* rho = (const float*)d_in[4];
    const float* eps = (const float*)d_in[5];
    // d_in[6] = H unused: applied via fast Walsh-Hadamard transform.
    float* out = (float*)d_out;

    int*   flags = (int*)d_ws;                          // 16 B (zeroed below)
    float* part2 = (float*)((char*)d_ws + 4096);        // [16][1024] 64 KB
    float* tg    = part2 + 16 * 1024;                   // [1024] 4 KB
    float* u     = tg + 1024;                           // [1024] 4 KB

    hipMemsetAsync(flags, 0, 64, stream);
    void* dummy = (void*)k_all;  (void)dummy;
    k_all<<<512, 512, 0, stream>>>(x, s1, s2, mu, rho, eps,
                                   flags, part2, tg, u, out);
}

// Round 13
// 32.460 us; speedup vs baseline: 9.3023x; 9.3023x over previous
//
#include <hip/hip_runtime.h>
#include <math.h>

#define DD 1024
#define BB 8192

__device__ __forceinline__ float softplus_f(float x) {
    return fmaxf(x, 0.0f) + log1pf(expf(-fabsf(x)));
}

// ---------------- kernel A: partials of t[j] = sum_i softplus(rho[i,j])*eps[i]
// 256 blocks = 16 colgroups x 16 rowgroups, fully coalesced, no atomics.
__global__ __launch_bounds__(256) void k_t(const float* __restrict__ rho,
                                           const float* __restrict__ eps,
                                           float* __restrict__ part) {
    const int tx = threadIdx.x, lane = tx & 63, w = tx >> 6;
    const int cg = blockIdx.x & 15, rg = blockIdx.x >> 4;
    const int j = cg * 64 + lane;
    const int rowbase = rg * 64 + w * 16;
    float acc = 0.f;
#pragma unroll
    for (int k = 0; k < 16; ++k) {
        int row = rowbase + k;
        acc += softplus_f(rho[row * DD + j]) * eps[row];
    }
    __shared__ float red[4][64];
    red[w][lane] = acc;
    __syncthreads();
    if (tx < 64) {
        float s = red[0][tx] + red[1][tx] + red[2][tx] + red[3][tx];
        part[(cg * 64 + tx) * 16 + rg] = s;
    }
}

// ---------------- kernel B: u[i] = mu[i] + sum_j softplus(rho[i,j]) * t[j] ----
__global__ __launch_bounds__(256) void k_u(const float* __restrict__ rho,
                                           const float* __restrict__ mu,
                                           const float* __restrict__ part,
                                           float* __restrict__ u) {
    int i  = blockIdx.x;      // 1024 blocks
    int tx = threadIdx.x;
    float acc = 0.f;
#pragma unroll
    for (int c = 0; c < 4; ++c) {
        int j = tx + c * 256;
        const float4* p4 = (const float4*)(part + j * 16);
        float4 a = p4[0], b = p4[1], cc = p4[2], dd = p4[3];
        float tj = ((a.x + a.y) + (a.z + a.w)) + ((b.x + b.y) + (b.z + b.w)) +
                   ((cc.x + cc.y) + (cc.z + cc.w)) + ((dd.x + dd.y) + (dd.z + dd.w));
        acc += softplus_f(rho[i * DD + j]) * tj;
    }
#pragma unroll
    for (int off = 32; off > 0; off >>= 1)
        acc += __shfl_down(acc, off, 64);
    __shared__ float red[4];
    int lane = tx & 63, w = tx >> 6;
    if (lane == 0) red[w] = acc;
    __syncthreads();
    if (tx == 0) u[i] = mu[i] + red[0] + red[1] + red[2] + red[3];
}

// ---------------- main: out[d,b] = relu(s1*FWHT(u*FWHT(s2*x_b))/1024) ---------

template <int CTRL>
__device__ __forceinline__ float dppmov(float x) {
    return __int_as_float(
        __builtin_amdgcn_mov_dpp(__float_as_int(x), CTRL, 0xF, 0xF, true));
}

__device__ __forceinline__ void fwht1024(float v[16], float sA, float sB,
                                         float sC, float sD, float sE, float sF) {
#pragma unroll
    for (int s = 1; s <= 8; s <<= 1) {
#pragma unroll
        for (int m = 0; m < 16; ++m)
            if ((m & s) == 0) {
                float a = v[m], b = v[m ^ s];
                v[m] = a + b;
                v[m ^ s] = a - b;
            }
    }
#pragma unroll
    for (int m = 0; m < 16; ++m) { float o = dppmov<0xB1>(v[m]);  v[m] = fmaf(v[m], sA, o); } // xor 1
#pragma unroll
    for (int m = 0; m < 16; ++m) { float o = dppmov<0x4E>(v[m]);  v[m] = fmaf(v[m], sB, o); } // xor 2
#pragma unroll
    for (int m = 0; m < 16; ++m) { float o = dppmov<0x141>(v[m]); v[m] = fmaf(v[m], sC, o); } // xor 7
#pragma unroll
    for (int m = 0; m < 16; ++m) { float o = dppmov<0x140>(v[m]); v[m] = fmaf(v[m], sD, o); } // xor 15
#pragma unroll
    for (int m = 0; m < 16; ++m) { float o = __shfl_xor(v[m], 16, 64); v[m] = fmaf(v[m], sE, o); } // xor 16
#pragma unroll
    for (int m = 0; m < 16; ++m) { float o = __shfl_xor(v[m], 32, 64); v[m] = fmaf(v[m], sF, o); } // xor 32
}

// 16 batches/block, 512 threads, f32 64KB tile, 2 blocks/CU. Block->batch map
// pairs the two blocks sharing each 128B output line onto the SAME XCD
// (XCD = bid%8; bid and bid+8 share an XCD) -> partial 64B writes merge to
// full lines in that XCD's L2. [R8-validated, 32.46us]
__global__ __launch_bounds__(512, 4) void k_main(const float* __restrict__ x,
                                                 const float* __restrict__ s1,
                                                 const float* __restrict__ s2,
                                                 const float* __restrict__ u,
                                                 float* __restrict__ out) {
    __shared__ __align__(16) float tile[16 * 1024];
    const int t    = threadIdx.x;
    const int lane = t & 63;
    const int wv   = t >> 6;
    const int bid  = blockIdx.x;        // 512 blocks
    const int x8   = bid & 7;           // XCD (bid%8 round-robin)
    const int q    = bid >> 3;          // 0..63
    const int pair = x8 * 32 + (q >> 1);        // same for q=2k,2k+1
    const int b0   = pair * 32 + (q & 1) * 16;  // bijective; line-pair same XCD

    const int l0 = lane & 1, l1 = (lane >> 1) & 1, l2 = (lane >> 2) & 1,
              l3 = (lane >> 3) & 1, l4 = (lane >> 4) & 1, l5 = (lane >> 5) & 1;
    const int hi = (l0 ^ l2) | ((l1 ^ l2) << 1) | ((l2 ^ l3) << 2) | (l3 << 3) |
                   (l4 << 4) | (l5 << 5);
    const int base = hi << 4;

    const float sA = (l0 ^ l2) ? -1.f : 1.f;
    const float sB = (l1 ^ l2) ? -1.f : 1.f;
    const float sC = (l2 ^ l3) ? -1.f : 1.f;
    const float sD = l3 ? -1.f : 1.f;
    const float sE = l4 ? -1.f : 1.f;
    const float sF = l5 ? -1.f : 1.f;

    float4 s2f[4], uf[4], s1f[4];
#pragma unroll
    for (int c = 0; c < 4; ++c) {
        s2f[c] = *(const float4*)(s2 + base + 4 * c);
        uf[c]  = *(const float4*)(u  + base + 4 * c);
        s1f[c] = *(const float4*)(s1 + base + 4 * c);
        const float kscale = 1.0f / 1024.0f;
        s1f[c].x *= kscale; s1f[c].y *= kscale;
        s1f[c].z *= kscale; s1f[c].w *= kscale;
    }
    const int qsw = hi & 3;

    for (int rr = 0; rr < 2; ++rr) {
        const int r = wv * 2 + rr;
        const float* xr = x + (size_t)(b0 + r) * DD + base;
        float v[16];
#pragma unroll
        for (int c = 0; c < 4; ++c) {
            float4 xv = *(const float4*)(xr + 4 * c);
            v[4 * c + 0] = xv.x * s2f[c].x;
            v[4 * c + 1] = xv.y * s2f[c].y;
            v[4 * c + 2] = xv.z * s2f[c].z;
            v[4 * c + 3] = xv.w * s2f[c].w;
        }
        fwht1024(v, sA, sB, sC, sD, sE, sF);
#pragma unroll
        for (int c = 0; c < 4; ++c) {
            v[4 * c + 0] *= uf[c].x;
            v[4 * c + 1] *= uf[c].y;
            v[4 * c + 2] *= uf[c].z;
            v[4 * c + 3] *= uf[c].w;
        }
        fwht1024(v, sA, sB, sC, sD, sE, sF);
        float* trow = tile + r * 1024 + ((hi ^ ((r >> 2) & 3)) << 4);
#pragma unroll
        for (int c = 0; c < 4; ++c) {
            float4 y;
            y.x = fmaxf(v[4 * c + 0] * s1f[c].x, 0.f);
            y.y = fmaxf(v[4 * c + 1] * s1f[c].y, 0.f);
            y.z = fmaxf(v[4 * c + 2] * s1f[c].z, 0.f);
            y.w = fmaxf(v[4 * c + 3] * s1f[c].w, 0.f);
            *(float4*)(trow + 4 * (c ^ qsw)) = y;
        }
    }
    __syncthreads();

#pragma unroll
    for (int it = 0; it < 8; ++it) {
        const int d  = (t >> 2) + (it << 7);
        const int r4 = (t & 3) << 2;
        const int h  = d >> 4;
        const int col = ((h ^ (t & 3)) << 4) + 4 * (((d >> 2) & 3) ^ (h & 3)) +
                        (d & 3);
        float4 y;
        y.x = tile[(r4 + 0) * 1024 + col];
        y.y = tile[(r4 + 1) * 1024 + col];
        y.z = tile[(r4 + 2) * 1024 + col];
        y.w = tile[(r4 + 3) * 1024 + col];
        *(float4*)(out + (size_t)d * BB + b0 + r4) = y;
    }
}

extern "C" void kernel_launch(void* const* d_in, const int* in_sizes, int n_in,
                              void* d_out, int out_size, void* d_ws, size_t ws_size,
                              hipStream_t stream) {
    const float* x   = (const float*)d_in[0];
    const float* s1  = (const float*)d_in[1];
    const float* s2  = (const float*)d_in[2];
    const float* mu  = (const float*)d_in[3];
    const float* rho = (const float*)d_in[4];
    const float* eps = (const float*)d_in[5];
    // d_in[6] = H unused: applied via fast Walsh-Hadamard transform.
    float* out = (float*)d_out;

    float* part = (float*)d_ws;      // [DD * 16] partials of t
    float* u    = part + DD * 16;    // [DD]

    k_t<<<256, 256, 0, stream>>>(rho, eps, part);
    k_u<<<DD, 256, 0, stream>>>(rho, mu, part, u);
    k_main<<<BB / 16, 512, 0, stream>>>(x, s1, s2, u, out);
}